// Round 1
// baseline (411.688 us; speedup 1.0000x reference)
//
#include <hip/hip_runtime.h>

#define Bn 4096
#define Tn 200
#define Fn 64
#define Gn 24   // 3*H, H=8

// ---------- fast math helpers ----------
__device__ __forceinline__ float frcp(float x) {
#if __has_builtin(__builtin_amdgcn_rcpf)
  return __builtin_amdgcn_rcpf(x);
#else
  return 1.0f / x;
#endif
}
__device__ __forceinline__ float fsigmoid(float x) {
  return frcp(1.0f + __expf(-x));
}
__device__ __forceinline__ float ftanh(float x) {
  x = fminf(30.0f, fmaxf(-30.0f, x));
  float t = __expf(-2.0f * x);
  return (1.0f - t) * frcp(1.0f + t);
}

// ---------- phase 1: x_proj[t][b][g] = x[b][t][:] . w_ih[g][:] + b_ih[g] ----------
// thread handles 4 consecutive t (one b); lane-contiguous b -> coalesced writes.
__global__ __launch_bounds__(256) void k_xproj(
    const float* __restrict__ x, const float* __restrict__ w_ih,
    const float* __restrict__ b_ih, float* __restrict__ xp) {
  __shared__ __align__(16) float wl[Gn * Fn];
  __shared__ float bsh[Gn];
  const int tid = threadIdx.x;
  #pragma unroll
  for (int i = 0; i < 2; ++i) {
    int idx = tid + i * 256;
    if (idx < (Gn * Fn) / 4)
      ((float4*)wl)[idx] = ((const float4*)w_ih)[idx];
  }
  if (tid < Gn) bsh[tid] = b_ih[tid];
  __syncthreads();

  const int n  = blockIdx.x * 256 + tid;   // 0 .. 204799
  const int b  = n & (Bn - 1);
  const int tq = n >> 12;                  // 0..49
  const int t0 = tq * 4;
  const float* xb = x + ((size_t)b * Tn + t0) * Fn;

  float acc[4][Gn];
  #pragma unroll
  for (int r = 0; r < 4; ++r)
    #pragma unroll
    for (int g = 0; g < Gn; ++g) acc[r][g] = bsh[g];

  #pragma unroll 1
  for (int fo = 0; fo < 4; ++fo) {       // 64-byte line per row per iter
    float4 xv[4][4];
    #pragma unroll
    for (int r = 0; r < 4; ++r)
      #pragma unroll
      for (int q = 0; q < 4; ++q)
        xv[r][q] = *(const float4*)(xb + (size_t)r * Fn + fo * 16 + q * 4);
    #pragma unroll
    for (int q = 0; q < 4; ++q) {
      const int f4 = fo * 4 + q;
      #pragma unroll
      for (int g = 0; g < Gn; ++g) {
        float4 w4 = ((const float4*)wl)[g * (Fn / 4) + f4];
        #pragma unroll
        for (int r = 0; r < 4; ++r) {
          acc[r][g] = fmaf(xv[r][q].x, w4.x, acc[r][g]);
          acc[r][g] = fmaf(xv[r][q].y, w4.y, acc[r][g]);
          acc[r][g] = fmaf(xv[r][q].z, w4.z, acc[r][g]);
          acc[r][g] = fmaf(xv[r][q].w, w4.w, acc[r][g]);
        }
      }
    }
  }
  #pragma unroll
  for (int r = 0; r < 4; ++r) {
    float* o = xp + ((size_t)(t0 + r) * Bn + b) * Gn;
    #pragma unroll
    for (int q = 0; q < Gn / 4; ++q) {
      float4 v = make_float4(acc[r][4*q], acc[r][4*q+1], acc[r][4*q+2], acc[r][4*q+3]);
      *(float4*)(o + 4 * q) = v;
    }
  }
}

// ---------- phase 2: sequential GRU scan ----------
// 512 blocks x 64 threads (1 wave). Block owns 8 batch elements; 8 lanes per b.
// Lane j owns hidden unit j (gates r_j, z_j, n_j). h replicated via LDS broadcast.
#define TC 20                       // timesteps per LDS chunk
#define NISS 15                     // (TC*8*Gn*4)/1024 = 15360/1024
#define NCH (Tn / TC)               // 10 chunks

__global__ __launch_bounds__(64) void k_gru(
    const float* __restrict__ xp, const float* __restrict__ w_hh,
    const float* __restrict__ b_hh, const float* __restrict__ w_dec,
    const float* __restrict__ b_dec, float* __restrict__ out) {
  __shared__ __align__(16) float sbuf[2][TC * 8 * Gn];  // 2 x 15360 B
  __shared__ float hls[64];

  const int lane = threadIdx.x;
  const int j  = lane & 7;
  const int bl = lane >> 3;
  const int b0 = blockIdx.x * 8;

  // per-lane recurrent weights (24 regs) + biases
  float whr[8], whz[8], whn[8];
  #pragma unroll
  for (int k = 0; k < 8; ++k) {
    whr[k] = w_hh[j * 8 + k];
    whz[k] = w_hh[(8 + j) * 8 + k];
    whn[k] = w_hh[(16 + j) * 8 + k];
  }
  const float bhr = b_hh[j], bhz = b_hh[8 + j], bhn = b_hh[16 + j];
  float wd[8];
  #pragma unroll
  for (int k = 0; k < 8; ++k) wd[k] = w_dec[k];
  const float bd = b_dec[0];

  float h[8];
  #pragma unroll
  for (int k = 0; k < 8; ++k) h[k] = 0.0f;
  float hown = 0.0f;   // this lane's own h[j] (avoid runtime-indexed reg array)

  const size_t row = (size_t)Bn * Gn;  // floats per t-slice

  auto issue_chunk = [&](int c, int sel) {
    const float* gb = xp + (size_t)c * TC * row + (size_t)b0 * Gn;
    #pragma unroll
    for (int k = 0; k < NISS; ++k) {
      int m   = k * 1024 + lane * 16;      // byte offset within chunk
      int tl  = m / 768;                   // 768 B per t-slice of this block
      int off = (m - tl * 768) >> 2;       // float offset
      const float* g = gb + (size_t)tl * row + off;
      float* l = &sbuf[sel][k * 256];      // uniform LDS base; HW adds lane*16
      __builtin_amdgcn_global_load_lds(
          (const __attribute__((address_space(1))) unsigned int*)g,
          (__attribute__((address_space(3))) unsigned int*)l, 16, 0, 0);
    }
  };

  issue_chunk(0, 0);
  asm volatile("s_waitcnt vmcnt(0)" ::: "memory");

  for (int c = 0; c < NCH; ++c) {
    const int cur = c & 1;
    if (c + 1 < NCH) issue_chunk(c + 1, cur ^ 1);  // prefetch overlaps compute

    const float* bb = &sbuf[cur][bl * Gn];
    #pragma unroll 4
    for (int tl = 0; tl < TC; ++tl) {
      const float* p = bb + tl * (8 * Gn);
      float xr = p[j], xz = p[8 + j], xn = p[16 + j];
      float ghr = bhr, ghz = bhz, ghn = bhn;
      #pragma unroll
      for (int k = 0; k < 8; ++k) {
        ghr = fmaf(whr[k], h[k], ghr);
        ghz = fmaf(whz[k], h[k], ghz);
        ghn = fmaf(whn[k], h[k], ghn);
      }
      float r  = fsigmoid(xr + ghr);
      float z  = fsigmoid(xz + ghz);
      float nv = ftanh(xn + r * ghn);
      float hj = fmaf(z, hown - nv, nv);   // (1-z)*n + z*h
      hls[lane] = hj;
      asm volatile("s_waitcnt lgkmcnt(0)" ::: "memory");
      #pragma unroll
      for (int k = 0; k < 8; ++k) h[k] = hls[bl * 8 + k];
      hown = hj;
    }
    if (c + 1 < NCH)
      asm volatile("s_waitcnt vmcnt(0)" ::: "memory");  // drain prefetch
  }

  if (j == 0) {
    float o = bd;
    #pragma unroll
    for (int k = 0; k < 8; ++k) o = fmaf(wd[k], h[k], o);
    out[b0 + bl] = o;
  }
}

extern "C" void kernel_launch(void* const* d_in, const int* in_sizes, int n_in,
                              void* d_out, int out_size, void* d_ws, size_t ws_size,
                              hipStream_t stream) {
  const float* x     = (const float*)d_in[0];
  const float* w_ih  = (const float*)d_in[1];
  const float* w_hh  = (const float*)d_in[2];
  const float* b_ih  = (const float*)d_in[3];
  const float* b_hh  = (const float*)d_in[4];
  const float* w_dec = (const float*)d_in[5];
  const float* b_dec = (const float*)d_in[6];
  float* out = (float*)d_out;
  float* xp  = (float*)d_ws;   // needs Bn*Tn*Gn*4 = 78,643,200 bytes

  k_xproj<<<dim3(800), dim3(256), 0, stream>>>(x, w_ih, b_ih, xp);
  k_gru<<<dim3(Bn / 8), dim3(64), 0, stream>>>(xp, w_hh, b_hh, w_dec, b_dec, out);
}

// Round 6
// 354.284 us; speedup vs baseline: 1.1620x; 1.1620x over previous
//
#include <hip/hip_runtime.h>

#define Bn 4096
#define Tn 200
#define Fn 64
#define Hn 8
#define Gn 24   // 3*H

typedef __attribute__((ext_vector_type(8))) short short8;
typedef __attribute__((ext_vector_type(4))) float f32x4;

// ---------- helpers ----------
__device__ __forceinline__ unsigned short bf16_rne(float f) {
  unsigned u = __float_as_uint(f);
  unsigned r = (u + 0x7FFFu + ((u >> 16) & 1u)) >> 16;
  return (unsigned short)r;
}
__device__ __forceinline__ float bf16_to_f(unsigned short s) {
  return __uint_as_float(((unsigned)s) << 16);
}
__device__ __forceinline__ float frcp(float x) {
#if __has_builtin(__builtin_amdgcn_rcpf)
  return __builtin_amdgcn_rcpf(x);
#else
  return 1.0f / x;
#endif
}
__device__ __forceinline__ float fsigmoid(float x) { return frcp(1.0f + __expf(-x)); }
__device__ __forceinline__ float ftanh(float x) {
  x = fminf(30.0f, fmaxf(-30.0f, x));
  float t = __expf(-2.0f * x);
  return (1.0f - t) * frcp(1.0f + t);
}
// cross-lane: xor1/xor2 via DPP quad_perm (VALU-fast), xor4 via ds_swizzle
__device__ __forceinline__ float xf1(float v) {
  return __int_as_float(__builtin_amdgcn_mov_dpp(__float_as_int(v), 0xB1, 0xF, 0xF, true)); // [1,0,3,2]
}
__device__ __forceinline__ float xf2(float v) {
  return __int_as_float(__builtin_amdgcn_mov_dpp(__float_as_int(v), 0x4E, 0xF, 0xF, true)); // [2,3,0,1]
}
__device__ __forceinline__ float xf4(float v) {
  return __int_as_float(__builtin_amdgcn_ds_swizzle(__float_as_int(v), 0x101F)); // xor lane^4
}

// ---------- phase 1: x_proj via bf16 MFMA with hi/lo split ----------
// wave w of block: b = blk*4+w. 13 tiles of 16 t (tail 8). Per tile:
// coalesced 4KB load -> bf16 hi/lo -> per-wave LDS transpose -> 12 MFMA -> store.
__global__ __launch_bounds__(256, 4) void k_xproj(
    const float* __restrict__ x, const float* __restrict__ w_ih,
    const float* __restrict__ b_ih, float* __restrict__ xp) {
  __shared__ unsigned short lds[4][2][16][68];  // [wave][hi/lo][m][68 bf16] rows=136B
  const int tid  = threadIdx.x;
  const int lane = tid & 63;
  const int w    = tid >> 6;
  const int b    = blockIdx.x * 4 + w;
  const int lm   = lane & 15;  // m (A rows) / n (B cols) / f4 (stage)
  const int lh   = lane >> 4;  // k-block

  // B fragments (W^T), hi/lo, 2 n-tiles x 2 k-tiles; bias per n-tile
  short8 Bh[2][2], Bl[2][2];
  float bias[2];
  #pragma unroll
  for (int nt = 0; nt < 2; ++nt) {
    int g = nt * 16 + lm;
    bool valid = (g < Gn);
    int gg = valid ? g : 0;
    bias[nt] = valid ? b_ih[gg] : 0.0f;
    #pragma unroll
    for (int kt = 0; kt < 2; ++kt) {
      int k0 = kt * 32 + lh * 8;
      const float* wp = w_ih + gg * Fn + k0;
      #pragma unroll
      for (int j = 0; j < 8; ++j) {
        float v = valid ? wp[j] : 0.0f;
        unsigned short hi = bf16_rne(v);
        float lo = v - bf16_to_f(hi);
        Bh[nt][kt][j] = (short)hi;
        Bl[nt][kt][j] = (short)bf16_rne(lo);
      }
    }
  }

  const float* xb = x + (size_t)b * Tn * Fn;

  for (int tau = 0; tau < 13; ++tau) {
    const int t0 = tau * 16;
    const int vrows = (t0 + 16 <= Tn) ? 16 : (Tn - t0);  // 16 or 8
    const int maxoff = vrows * Fn;                        // 1024 or 512 floats (pow2)
    const float* tb = xb + (size_t)t0 * Fn;

    // stage: coalesced loads + convert + LDS transpose-write
    #pragma unroll
    for (int q = 0; q < 4; ++q) {
      int off = (q * 256 + lane * 4) & (maxoff - 1);
      float4 v = *(const float4*)(tb + off);
      int m  = q * 4 + lh;
      int f4 = lm;
      unsigned short h0 = bf16_rne(v.x), h1 = bf16_rne(v.y),
                     h2 = bf16_rne(v.z), h3 = bf16_rne(v.w);
      float l0 = v.x - bf16_to_f(h0), l1 = v.y - bf16_to_f(h1),
            l2 = v.z - bf16_to_f(h2), l3 = v.w - bf16_to_f(h3);
      uint2 hw, lw;
      hw.x = (unsigned)h0 | ((unsigned)h1 << 16);
      hw.y = (unsigned)h2 | ((unsigned)h3 << 16);
      lw.x = (unsigned)bf16_rne(l0) | ((unsigned)bf16_rne(l1) << 16);
      lw.y = (unsigned)bf16_rne(l2) | ((unsigned)bf16_rne(l3) << 16);
      *(uint2*)&lds[w][0][m][f4 * 4] = hw;
      *(uint2*)&lds[w][1][m][f4 * 4] = lw;
    }

    // A fragments + MFMA
    f32x4 c[2] = {{0.f,0.f,0.f,0.f},{0.f,0.f,0.f,0.f}};
    #pragma unroll
    for (int kt = 0; kt < 2; ++kt) {
      const unsigned short* ph = &lds[w][0][lm][kt * 32 + lh * 8];
      const unsigned short* pl = &lds[w][1][lm][kt * 32 + lh * 8];
      uint2 dh0 = *(const uint2*)ph;
      uint2 dh1 = *(const uint2*)(ph + 4);
      uint2 dl0 = *(const uint2*)pl;
      uint2 dl1 = *(const uint2*)(pl + 4);
      union { unsigned int u[4]; short8 s; } Ah, Al;
      Ah.u[0] = dh0.x; Ah.u[1] = dh0.y; Ah.u[2] = dh1.x; Ah.u[3] = dh1.y;
      Al.u[0] = dl0.x; Al.u[1] = dl0.y; Al.u[2] = dl1.x; Al.u[3] = dl1.y;
      #pragma unroll
      for (int nt = 0; nt < 2; ++nt) {
        c[nt] = __builtin_amdgcn_mfma_f32_16x16x32_bf16(Ah.s, Bh[nt][kt], c[nt], 0, 0, 0);
        c[nt] = __builtin_amdgcn_mfma_f32_16x16x32_bf16(Ah.s, Bl[nt][kt], c[nt], 0, 0, 0);
        c[nt] = __builtin_amdgcn_mfma_f32_16x16x32_bf16(Al.s, Bh[nt][kt], c[nt], 0, 0, 0);
      }
    }

    // store: C row = lh*4+i, col = lm  [m89 layout]
    #pragma unroll
    for (int nt = 0; nt < 2; ++nt) {
      if (nt == 1 && lm >= Gn - 16) continue;  // g >= 24
      int g = nt * 16 + lm;
      #pragma unroll
      for (int i = 0; i < 4; ++i) {
        int row = lh * 4 + i;
        if (row < vrows)
          xp[((size_t)(t0 + row) * Bn + b) * Gn + g] = c[nt][i] + bias[nt];
      }
    }
  }
}

// ---------- phase 2: GRU scan, register butterfly h-broadcast ----------
#define TC 20
#define NISS 15   // (TC*8*Gn*4)/1024
#define NCH (Tn / TC)

__global__ __launch_bounds__(64) void k_gru(
    const float* __restrict__ xp, const float* __restrict__ w_hh,
    const float* __restrict__ b_hh, const float* __restrict__ w_dec,
    const float* __restrict__ b_dec, float* __restrict__ out) {
  __shared__ __align__(16) float sbuf[2][TC * 8 * Gn];  // 2 x 15360 B

  const int lane = threadIdx.x & 63;
  const int j  = lane & 7;
  const int bl = lane >> 3;
  const int b0 = blockIdx.x * 8;

  // per-lane recurrent weights, PERMUTED so whX[k] multiplies h[j^k]
  float whr[8], whz[8], whn[8];
  #pragma unroll
  for (int k = 0; k < 8; ++k) {
    int col = j ^ k;
    whr[k] = w_hh[j * 8 + col];
    whz[k] = w_hh[(8 + j) * 8 + col];
    whn[k] = w_hh[(16 + j) * 8 + col];
  }
  const float bhr = b_hh[j], bhz = b_hh[8 + j], bhn = b_hh[16 + j];
  float wd[8];
  #pragma unroll
  for (int k = 0; k < 8; ++k) wd[k] = w_dec[k];
  const float bd = b_dec[0];

  float g[8];
  #pragma unroll
  for (int k = 0; k < 8; ++k) g[k] = 0.0f;   // g[k] = h[j^k]

  const size_t row = (size_t)Bn * Gn;

  auto issue_chunk = [&](int c, int sel) {
    const float* gb = xp + (size_t)c * TC * row + (size_t)b0 * Gn;
    #pragma unroll
    for (int k = 0; k < NISS; ++k) {
      int m   = k * 1024 + lane * 16;
      int tl  = m / 768;
      int off = (m - tl * 768) >> 2;
      const float* gp = gb + (size_t)tl * row + off;
      float* l = &sbuf[sel][k * 256];
      __builtin_amdgcn_global_load_lds(
          (const __attribute__((address_space(1))) unsigned int*)gp,
          (__attribute__((address_space(3))) unsigned int*)l, 16, 0, 0);
    }
  };

  issue_chunk(0, 0);
  asm volatile("s_waitcnt vmcnt(0)" ::: "memory");

  float xr = sbuf[0][bl * Gn + j];
  float xz = sbuf[0][bl * Gn + 8 + j];
  float xn = sbuf[0][bl * Gn + 16 + j];

  for (int c = 0; c < NCH; ++c) {
    const int cur = c & 1;
    if (c + 1 < NCH) issue_chunk(c + 1, cur ^ 1);  // prefetch overlaps compute

    const float* bb = &sbuf[cur][bl * Gn];
    #pragma unroll 5
    for (int tl = 0; tl < TC; ++tl) {
      // issue next-step x reads early (hides LDS latency under compute)
      float nxr = 0.f, nxz = 0.f, nxn = 0.f;
      if (tl + 1 < TC) {
        const float* p = bb + (tl + 1) * (8 * Gn);
        nxr = p[j]; nxz = p[8 + j]; nxn = p[16 + j];
      }
      float ghr = bhr, ghz = bhz, ghn = bhn;
      #pragma unroll
      for (int k = 0; k < 8; ++k) {
        ghr = fmaf(whr[k], g[k], ghr);
        ghz = fmaf(whz[k], g[k], ghz);
        ghn = fmaf(whn[k], g[k], ghn);
      }
      float r  = fsigmoid(xr + ghr);
      float z  = fsigmoid(xz + ghz);
      float nv = ftanh(xn + r * ghn);
      float hj = fmaf(z, g[0] - nv, nv);   // (1-z)*n + z*h
      // butterfly all-gather: g[k] = h[j^k]
      g[0] = hj;
      g[1] = xf1(g[0]);
      g[2] = xf2(g[0]); g[3] = xf2(g[1]);
      g[4] = xf4(g[0]); g[5] = xf4(g[1]); g[6] = xf4(g[2]); g[7] = xf4(g[3]);
      xr = nxr; xz = nxz; xn = nxn;
    }
    if (c + 1 < NCH) {
      asm volatile("s_waitcnt vmcnt(0)" ::: "memory");  // drain prefetch
      const float* p = &sbuf[cur ^ 1][bl * Gn];
      xr = p[j]; xz = p[8 + j]; xn = p[16 + j];
    }
  }

  if (j == 0) {
    float o = bd;
    #pragma unroll
    for (int k = 0; k < 8; ++k) o = fmaf(wd[k], g[k], o);  // lane j=0: g[k] = h[k]
    out[b0 + bl] = o;
  }
}

extern "C" void kernel_launch(void* const* d_in, const int* in_sizes, int n_in,
                              void* d_out, int out_size, void* d_ws, size_t ws_size,
                              hipStream_t stream) {
  const float* x     = (const float*)d_in[0];
  const float* w_ih  = (const float*)d_in[1];
  const float* w_hh  = (const float*)d_in[2];
  const float* b_ih  = (const float*)d_in[3];
  const float* b_hh  = (const float*)d_in[4];
  const float* w_dec = (const float*)d_in[5];
  const float* b_dec = (const float*)d_in[6];
  float* out = (float*)d_out;
  float* xp  = (float*)d_ws;   // Bn*Tn*Gn*4 = 78,643,200 bytes

  k_xproj<<<dim3(Bn / 4), dim3(256), 0, stream>>>(x, w_ih, b_ih, xp);
  k_gru<<<dim3(Bn / 8), dim3(64), 0, stream>>>(xp, w_hh, b_hh, w_dec, b_dec, out);
}

// Round 7
// 319.648 us; speedup vs baseline: 1.2879x; 1.1084x over previous
//
#include <hip/hip_runtime.h>

#define Bn 4096
#define Tn 200
#define Fn 64
#define Hn 8
#define Gn 24   // 3*H
#define TC 8    // timesteps per chunk (no tail: 25*8=200)
#define NCH 25
#define ROWF 68 // padded floats per (bl,tl) row (bank-spread for b128 reads)
#define NLD 17  // global_load_lds instrs per chunk: 8*8*68*4B / 1024B

typedef __attribute__((ext_vector_type(8))) short short8;
typedef __attribute__((ext_vector_type(4))) float f32x4;

// ---------- helpers ----------
__device__ __forceinline__ unsigned short bf16_rne(float f) {
  unsigned u = __float_as_uint(f);
  unsigned r = (u + 0x7FFFu + ((u >> 16) & 1u)) >> 16;
  return (unsigned short)r;
}
__device__ __forceinline__ float bf16_to_f(unsigned short s) {
  return __uint_as_float(((unsigned)s) << 16);
}
__device__ __forceinline__ float frcp(float x) {
#if __has_builtin(__builtin_amdgcn_rcpf)
  return __builtin_amdgcn_rcpf(x);
#else
  return 1.0f / x;
#endif
}
__device__ __forceinline__ float fsigmoid(float x) { return frcp(1.0f + __expf(-x)); }
__device__ __forceinline__ float ftanh(float x) {
  x = fminf(30.0f, fmaxf(-30.0f, x));
  float t = __expf(-2.0f * x);
  return (1.0f - t) * frcp(1.0f + t);
}
// cross-lane: xor1/xor2 via DPP quad_perm, xor4 via ds_swizzle (validated R6)
__device__ __forceinline__ float xf1(float v) {
  return __int_as_float(__builtin_amdgcn_mov_dpp(__float_as_int(v), 0xB1, 0xF, 0xF, true));
}
__device__ __forceinline__ float xf2(float v) {
  return __int_as_float(__builtin_amdgcn_mov_dpp(__float_as_int(v), 0x4E, 0xF, 0xF, true));
}
__device__ __forceinline__ float xf4(float v) {
  return __int_as_float(__builtin_amdgcn_ds_swizzle(__float_as_int(v), 0x101F));
}
// fp32 -> bf16 hi/lo split of 8 contiguous values (validated R6)
__device__ __forceinline__ void cvt_hilo(const float4& a, const float4& b,
                                         short8& hi, short8& lo) {
  float v[8] = {a.x, a.y, a.z, a.w, b.x, b.y, b.z, b.w};
  #pragma unroll
  for (int i = 0; i < 8; ++i) {
    unsigned short h = bf16_rne(v[i]);
    hi[i] = (short)h;
    lo[i] = (short)bf16_rne(v[i] - bf16_to_f(h));
  }
}

// ---------- fused: x-projection (MFMA, hi/lo bf16) + GRU scan + decode ----------
// 512 blocks x 64 threads. Block owns 8 b. Per 8-t chunk:
//   issue next chunk's global_load_lds (vmcnt(17) counted wait)
//   proj: 4 b-pairs, MFMA m=16=(2b x 8t), n=24(g), k=64(f) -> pbuf[tl][bl][g]
//   scan: 8 steps, butterfly h-broadcast, h in registers across chunks
__global__ __launch_bounds__(64) void k_fused(
    const float* __restrict__ x, const float* __restrict__ w_ih,
    const float* __restrict__ w_hh, const float* __restrict__ b_ih,
    const float* __restrict__ b_hh, const float* __restrict__ w_dec,
    const float* __restrict__ b_dec, float* __restrict__ out) {
  __shared__ __align__(16) float xbuf[2][8][TC][ROWF];  // 34816 B
  __shared__ __align__(16) float pbuf[TC][8][Gn];       //  6144 B

  const int lane = threadIdx.x & 63;
  const int j  = lane & 7;
  const int bl = lane >> 3;
  const int lm = lane & 15;
  const int lh = lane >> 4;
  const int b0 = blockIdx.x * 8;

  // ---- B fragments of w_ih (hi/lo), bias (validated R6 layout) ----
  short8 Bh[2][2], Bl[2][2];
  float bias[2];
  #pragma unroll
  for (int nt = 0; nt < 2; ++nt) {
    int gg0 = nt * 16 + lm;
    bool valid = (gg0 < Gn);
    int gg = valid ? gg0 : 0;
    bias[nt] = valid ? b_ih[gg] : 0.0f;
    #pragma unroll
    for (int kt = 0; kt < 2; ++kt) {
      const float* wp = w_ih + gg * Fn + kt * 32 + lh * 8;
      #pragma unroll
      for (int q = 0; q < 8; ++q) {
        float v = valid ? wp[q] : 0.0f;
        unsigned short hh = bf16_rne(v);
        Bh[nt][kt][q] = (short)hh;
        Bl[nt][kt][q] = (short)bf16_rne(v - bf16_to_f(hh));
      }
    }
  }

  // ---- recurrent weights, butterfly-permuted: whX[k] multiplies h[j^k] ----
  float whr[8], whz[8], whn[8];
  #pragma unroll
  for (int k = 0; k < 8; ++k) {
    int col = j ^ k;
    whr[k] = w_hh[j * 8 + col];
    whz[k] = w_hh[(8 + j) * 8 + col];
    whn[k] = w_hh[(16 + j) * 8 + col];
  }
  const float bhr = b_hh[j], bhz = b_hh[8 + j], bhn = b_hh[16 + j];
  float wd[8];
  #pragma unroll
  for (int k = 0; k < 8; ++k) wd[k] = w_dec[k];
  const float bd = b_dec[0];

  // ---- per-lane chunk-load source offsets (pad granule 17 -> clamp) ----
  // LDS granule (16B) g = i*64+lane; row = g/17 = bl*8+tl; colg = g%17.
  unsigned coff[NLD];
  #pragma unroll
  for (int i = 0; i < NLD; ++i) {
    unsigned gr  = (unsigned)(i * 64 + lane);
    unsigned row = gr / 17u;
    unsigned cg  = gr - row * 17u;
    coff[i] = ((row >> 3) * Tn + (row & 7)) * Fn + (cg < 16u ? cg * 4u : 0u);
  }
  const float* xb = x + (size_t)b0 * Tn * Fn;

  auto issue = [&](int c, int sel) {
    const float* gb = xb + c * (TC * Fn);
    float* lbase = &xbuf[sel][0][0][0];
    #pragma unroll
    for (int i = 0; i < NLD; ++i) {
      __builtin_amdgcn_global_load_lds(
          (const __attribute__((address_space(1))) unsigned int*)(gb + coff[i]),
          (__attribute__((address_space(3))) unsigned int*)(lbase + i * 256),
          16, 0, 0);
    }
  };

  issue(0, 0);

  float g[8];
  #pragma unroll
  for (int k = 0; k < 8; ++k) g[k] = 0.0f;

  #pragma unroll 1
  for (int c = 0; c < NCH; ++c) {
    const int sel = c & 1;
    if (c + 1 < NCH) {
      issue(c + 1, sel ^ 1);
      asm volatile("s_waitcnt vmcnt(17)" ::: "memory");  // chunk c resident
    } else {
      asm volatile("s_waitcnt vmcnt(0)" ::: "memory");
    }

    // ---- projection: 4 b-pairs, each one 16x24x64 tile ----
    #pragma unroll
    for (int bp = 0; bp < 4; ++bp) {
      const float* ab = &xbuf[sel][bp * 2 + (lm >> 3)][lm & 7][lh * 8];
      float4 f0 = *(const float4*)ab;
      float4 f1 = *(const float4*)(ab + 4);
      float4 f2 = *(const float4*)(ab + 32);
      float4 f3 = *(const float4*)(ab + 36);
      short8 Ah0, Al0, Ah1, Al1;
      cvt_hilo(f0, f1, Ah0, Al0);
      cvt_hilo(f2, f3, Ah1, Al1);

      f32x4 c0 = {0.f, 0.f, 0.f, 0.f}, c1 = {0.f, 0.f, 0.f, 0.f};
      c0 = __builtin_amdgcn_mfma_f32_16x16x32_bf16(Ah0, Bh[0][0], c0, 0, 0, 0);
      c0 = __builtin_amdgcn_mfma_f32_16x16x32_bf16(Ah0, Bl[0][0], c0, 0, 0, 0);
      c0 = __builtin_amdgcn_mfma_f32_16x16x32_bf16(Al0, Bh[0][0], c0, 0, 0, 0);
      c0 = __builtin_amdgcn_mfma_f32_16x16x32_bf16(Ah1, Bh[0][1], c0, 0, 0, 0);
      c0 = __builtin_amdgcn_mfma_f32_16x16x32_bf16(Ah1, Bl[0][1], c0, 0, 0, 0);
      c0 = __builtin_amdgcn_mfma_f32_16x16x32_bf16(Al1, Bh[0][1], c0, 0, 0, 0);
      c1 = __builtin_amdgcn_mfma_f32_16x16x32_bf16(Ah0, Bh[1][0], c1, 0, 0, 0);
      c1 = __builtin_amdgcn_mfma_f32_16x16x32_bf16(Ah0, Bl[1][0], c1, 0, 0, 0);
      c1 = __builtin_amdgcn_mfma_f32_16x16x32_bf16(Al0, Bh[1][0], c1, 0, 0, 0);
      c1 = __builtin_amdgcn_mfma_f32_16x16x32_bf16(Ah1, Bh[1][1], c1, 0, 0, 0);
      c1 = __builtin_amdgcn_mfma_f32_16x16x32_bf16(Ah1, Bl[1][1], c1, 0, 0, 0);
      c1 = __builtin_amdgcn_mfma_f32_16x16x32_bf16(Al1, Bh[1][1], c1, 0, 0, 0);

      // C layout (m89): col = lm (g), row = lh*4+i2 (= bp-local m)
      #pragma unroll
      for (int i2 = 0; i2 < 4; ++i2) {
        int m   = lh * 4 + i2;
        int tl  = m & 7;
        int blw = bp * 2 + (m >> 3);
        pbuf[tl][blw][lm] = c0[i2] + bias[0];
        if (lm < 8) pbuf[tl][blw][16 + lm] = c1[i2] + bias[1];
      }
    }
    asm volatile("s_waitcnt lgkmcnt(0)" ::: "memory");  // 1 wave: no barrier needed

    // ---- scan 8 steps (validated R6 butterfly) ----
    const float* bb = &pbuf[0][bl][0];
    float xr = bb[j], xz = bb[8 + j], xn = bb[16 + j];
    #pragma unroll
    for (int tl = 0; tl < TC; ++tl) {
      float nxr = 0.f, nxz = 0.f, nxn = 0.f;
      if (tl + 1 < TC) {
        const float* p = bb + (tl + 1) * (8 * Gn);
        nxr = p[j]; nxz = p[8 + j]; nxn = p[16 + j];
      }
      float ghr = bhr, ghz = bhz, ghn = bhn;
      #pragma unroll
      for (int k = 0; k < 8; ++k) {
        ghr = fmaf(whr[k], g[k], ghr);
        ghz = fmaf(whz[k], g[k], ghz);
        ghn = fmaf(whn[k], g[k], ghn);
      }
      float r  = fsigmoid(xr + ghr);
      float z  = fsigmoid(xz + ghz);
      float nv = ftanh(xn + r * ghn);
      float hj = fmaf(z, g[0] - nv, nv);   // (1-z)*n + z*h
      g[0] = hj;
      g[1] = xf1(g[0]);
      g[2] = xf2(g[0]); g[3] = xf2(g[1]);
      g[4] = xf4(g[0]); g[5] = xf4(g[1]); g[6] = xf4(g[2]); g[7] = xf4(g[3]);
      xr = nxr; xz = nxz; xn = nxn;
    }
  }

  if (j == 0) {
    float o = bd;
    #pragma unroll
    for (int k = 0; k < 8; ++k) o = fmaf(wd[k], g[k], o);  // lane j=0: g[k]=h[k]
    out[b0 + bl] = o;
  }
}

extern "C" void kernel_launch(void* const* d_in, const int* in_sizes, int n_in,
                              void* d_out, int out_size, void* d_ws, size_t ws_size,
                              hipStream_t stream) {
  const float* x     = (const float*)d_in[0];
  const float* w_ih  = (const float*)d_in[1];
  const float* w_hh  = (const float*)d_in[2];
  const float* b_ih  = (const float*)d_in[3];
  const float* b_hh  = (const float*)d_in[4];
  const float* w_dec = (const float*)d_in[5];
  const float* b_dec = (const float*)d_in[6];
  float* out = (float*)d_out;
  (void)d_ws; (void)ws_size;  // no workspace: xp eliminated by fusion

  k_fused<<<dim3(Bn / 8), dim3(64), 0, stream>>>(x, w_ih, w_hh, b_ih, b_hh,
                                                 w_dec, b_dec, out);
}

// Round 9
// 306.923 us; speedup vs baseline: 1.3413x; 1.0415x over previous
//
#include <hip/hip_runtime.h>

#define Bn 4096
#define Tn 200
#define Fn 64
#define Hn 8
#define Gn 24   // 3*H
#define TC 8    // timesteps per chunk (25*8 = 200, no tail)
#define NCH 25
#define ROWF 68 // padded floats per (b,t) row
#define NLD 17  // global_load_lds per chunk: 8*8*68*4B / 1024B

typedef __attribute__((ext_vector_type(8))) short short8;
typedef __attribute__((ext_vector_type(4))) float f32x4;

// ---------- helpers ----------
__device__ __forceinline__ unsigned short bf16_rne(float f) {
  unsigned u = __float_as_uint(f);
  return (unsigned short)((u + 0x7FFFu + ((u >> 16) & 1u)) >> 16);
}
__device__ __forceinline__ float bf16_to_f(unsigned short s) {
  return __uint_as_float(((unsigned)s) << 16);
}
__device__ __forceinline__ float frcp(float x) {
#if __has_builtin(__builtin_amdgcn_rcpf)
  return __builtin_amdgcn_rcpf(x);
#else
  return 1.0f / x;
#endif
}
__device__ __forceinline__ float fsigmoid(float x) { return frcp(1.0f + __expf(-x)); }
__device__ __forceinline__ float ftanh(float x) {
  x = fminf(30.0f, fmaxf(-30.0f, x));
  float t = __expf(-2.0f * x);
  return (1.0f - t) * frcp(1.0f + t);
}
// cross-lane, all DPP (VALU pipe, no LDS): xor1, xor2 quad_perm; xor7 row_half_mirror
__device__ __forceinline__ float xf1(float v) {
  return __int_as_float(__builtin_amdgcn_mov_dpp(__float_as_int(v), 0xB1, 0xF, 0xF, true));
}
__device__ __forceinline__ float xf2(float v) {
  return __int_as_float(__builtin_amdgcn_mov_dpp(__float_as_int(v), 0x4E, 0xF, 0xF, true));
}
__device__ __forceinline__ float xf7(float v) {
  return __int_as_float(__builtin_amdgcn_mov_dpp(__float_as_int(v), 0x141, 0xF, 0xF, true));
}
// packed f32x2 -> bf16x2 RNE (no builtin on gfx950; asm per guide m240)
__device__ __forceinline__ unsigned cvt_pk_bf16(float a, float b) {
  unsigned r;
  asm volatile("v_cvt_pk_bf16_f32 %0, %1, %2" : "=v"(r) : "v"(a), "v"(b));
  return r;
}
// trunc-split: hi = bits-truncated bf16 (exact), lo = RNE(bf16) of exact residual
__device__ __forceinline__ void split8(const float4& A, const float4& B,
                                       short8& hi, short8& lo) {
  float v[8] = {A.x, A.y, A.z, A.w, B.x, B.y, B.z, B.w};
  union { unsigned u[4]; short8 s; } H, L;
  #pragma unroll
  for (int p = 0; p < 4; ++p) {
    unsigned u0 = __float_as_uint(v[2 * p]), u1 = __float_as_uint(v[2 * p + 1]);
    float h0 = __uint_as_float(u0 & 0xFFFF0000u);
    float h1 = __uint_as_float(u1 & 0xFFFF0000u);
    H.u[p] = (u0 >> 16) | (u1 & 0xFFFF0000u);
    L.u[p] = cvt_pk_bf16(v[2 * p] - h0, v[2 * p + 1] - h1);
  }
  hi = H.s; lo = L.s;
}

// ---------- fused GRU: proj(c+1) MFMA pipelined against scan(c) VALU ----------
__global__ __launch_bounds__(64) void k_fused(
    const float* __restrict__ x, const float* __restrict__ w_ih,
    const float* __restrict__ w_hh, const float* __restrict__ b_ih,
    const float* __restrict__ b_hh, const float* __restrict__ w_dec,
    const float* __restrict__ b_dec, float* __restrict__ out) {
  __shared__ __align__(16) float xbuf[2][8][TC][ROWF];  // 34816 B
  __shared__ __align__(16) float pbuf[2][TC][8][Gn];    // 12288 B

  const int lane = threadIdx.x & 63;
  const int j  = lane & 7;
  const int bl = lane >> 3;
  const int lm = lane & 15;
  const int lh = lane >> 4;
  const int b0 = blockIdx.x * 8;

  // ---- B fragments of w_ih (hi/lo RNE, one-time), bias (R6-validated) ----
  short8 Bh[2][2], Bl[2][2];
  float bias[2];
  #pragma unroll
  for (int nt = 0; nt < 2; ++nt) {
    int gg0 = nt * 16 + lm;
    bool valid = (gg0 < Gn);
    int gg = valid ? gg0 : 0;
    bias[nt] = valid ? b_ih[gg] : 0.0f;
    #pragma unroll
    for (int kt = 0; kt < 2; ++kt) {
      const float* wp = w_ih + gg * Fn + kt * 32 + lh * 8;
      #pragma unroll
      for (int q = 0; q < 8; ++q) {
        float v = valid ? wp[q] : 0.0f;
        unsigned short hh = bf16_rne(v);
        Bh[nt][kt][q] = (short)hh;
        Bl[nt][kt][q] = (short)bf16_rne(v - bf16_to_f(hh));
      }
    }
  }

  // ---- recurrent weights, butterfly-permuted: whX[k] multiplies h[j^k] ----
  float whr[8], whz[8], whn[8];
  #pragma unroll
  for (int k = 0; k < 8; ++k) {
    int col = j ^ k;
    whr[k] = w_hh[j * 8 + col];
    whz[k] = w_hh[(8 + j) * 8 + col];
    whn[k] = w_hh[(16 + j) * 8 + col];
  }
  const float bhr = b_hh[j], bhz = b_hh[8 + j], bhn = b_hh[16 + j];
  float wd[8];
  #pragma unroll
  for (int k = 0; k < 8; ++k) wd[k] = w_dec[k];
  const float bd = b_dec[0];

  // ---- per-lane chunk-load source offsets (pad granule clamped) ----
  unsigned coff[NLD];
  #pragma unroll
  for (int i = 0; i < NLD; ++i) {
    unsigned gr  = (unsigned)(i * 64 + lane);
    unsigned row = gr / 17u;
    unsigned cg  = gr - row * 17u;
    coff[i] = ((row >> 3) * Tn + (row & 7)) * Fn + (cg < 16u ? cg * 4u : 0u);
  }
  const float* xb = x + (size_t)b0 * Tn * Fn;

  auto issue = [&](int c, int sel) {
    const float* gb = xb + c * (TC * Fn);
    float* lbase = &xbuf[sel][0][0][0];
    #pragma unroll
    for (int i = 0; i < NLD; ++i) {
      __builtin_amdgcn_global_load_lds(
          (const __attribute__((address_space(1))) unsigned int*)(gb + coff[i]),
          (__attribute__((address_space(3))) unsigned int*)(lbase + i * 256),
          16, 0, 0);
    }
  };

  // proj one b-pair: LDS reads -> trunc-split -> 12 MFMA (acc returned in regs)
  auto proj_bp = [&](int bp, int xsel, f32x4& c0, f32x4& c1) {
    const float* ab = &xbuf[xsel][bp * 2 + (lm >> 3)][lm & 7][lh * 8];
    float4 f0 = *(const float4*)ab;
    float4 f1 = *(const float4*)(ab + 4);
    float4 f2 = *(const float4*)(ab + 32);
    float4 f3 = *(const float4*)(ab + 36);
    short8 Ah0, Al0, Ah1, Al1;
    split8(f0, f1, Ah0, Al0);
    split8(f2, f3, Ah1, Al1);
    c0 = (f32x4){0.f, 0.f, 0.f, 0.f};
    c1 = (f32x4){0.f, 0.f, 0.f, 0.f};
    c0 = __builtin_amdgcn_mfma_f32_16x16x32_bf16(Ah0, Bh[0][0], c0, 0, 0, 0);
    c0 = __builtin_amdgcn_mfma_f32_16x16x32_bf16(Ah0, Bl[0][0], c0, 0, 0, 0);
    c0 = __builtin_amdgcn_mfma_f32_16x16x32_bf16(Al0, Bh[0][0], c0, 0, 0, 0);
    c0 = __builtin_amdgcn_mfma_f32_16x16x32_bf16(Ah1, Bh[0][1], c0, 0, 0, 0);
    c0 = __builtin_amdgcn_mfma_f32_16x16x32_bf16(Ah1, Bl[0][1], c0, 0, 0, 0);
    c0 = __builtin_amdgcn_mfma_f32_16x16x32_bf16(Al1, Bh[0][1], c0, 0, 0, 0);
    c1 = __builtin_amdgcn_mfma_f32_16x16x32_bf16(Ah0, Bh[1][0], c1, 0, 0, 0);
    c1 = __builtin_amdgcn_mfma_f32_16x16x32_bf16(Ah0, Bl[1][0], c1, 0, 0, 0);
    c1 = __builtin_amdgcn_mfma_f32_16x16x32_bf16(Al0, Bh[1][0], c1, 0, 0, 0);
    c1 = __builtin_amdgcn_mfma_f32_16x16x32_bf16(Ah1, Bh[1][1], c1, 0, 0, 0);
    c1 = __builtin_amdgcn_mfma_f32_16x16x32_bf16(Ah1, Bl[1][1], c1, 0, 0, 0);
    c1 = __builtin_amdgcn_mfma_f32_16x16x32_bf16(Al1, Bh[1][1], c1, 0, 0, 0);
  };
  auto write_bp = [&](int bp, int psel, const f32x4& c0, const f32x4& c1) {
    #pragma unroll
    for (int i2 = 0; i2 < 4; ++i2) {
      int m = lh * 4 + i2, tl = m & 7, blw = bp * 2 + (m >> 3);
      pbuf[psel][tl][blw][lm] = c0[i2] + bias[0];
      if (lm < 8) pbuf[psel][tl][blw][16 + lm] = c1[i2] + bias[1];
    }
  };

  float g[8];
  #pragma unroll
  for (int k = 0; k < 8; ++k) g[k] = 0.0f;
  float xr, xz, xn;

  // one scan step; expects xr/xz/xn preloaded, prefetches step tl+1
  auto step = [&](const float* bb, int tl) {
    float nxr = 0.f, nxz = 0.f, nxn = 0.f;
    if (tl + 1 < TC) {
      const float* p = bb + (tl + 1) * (8 * Gn);
      nxr = p[j]; nxz = p[8 + j]; nxn = p[16 + j];
    }
    float ghr = bhr, ghz = bhz, ghn = bhn;
    const int ko[8] = {0, 1, 2, 3, 7, 6, 5, 4};  // deepest-DPP value last
    #pragma unroll
    for (int q = 0; q < 8; ++q) {
      int k = ko[q];
      ghr = fmaf(whr[k], g[k], ghr);
      ghz = fmaf(whz[k], g[k], ghz);
      ghn = fmaf(whn[k], g[k], ghn);
    }
    float r  = fsigmoid(xr + ghr);
    float z  = fsigmoid(xz + ghz);
    float nv = ftanh(xn + r * ghn);
    float hj = fmaf(z, g[0] - nv, nv);   // (1-z)*n + z*h
    g[0] = hj;
    g[1] = xf1(g[0]); g[2] = xf2(g[0]); g[3] = xf2(g[1]);
    g[7] = xf7(g[0]); g[6] = xf7(g[1]); g[5] = xf7(g[2]); g[4] = xf7(g[3]);
    xr = nxr; xz = nxz; xn = nxn;
  };

  // ---- prologue: chunks 0,1 in flight; proj(0) ----
  issue(0, 0);
  issue(1, 1);
  asm volatile("s_waitcnt vmcnt(17)" ::: "memory");  // chunk 0 resident
  {
    f32x4 t0, t1;
    #pragma unroll
    for (int bp = 0; bp < 4; ++bp) { proj_bp(bp, 0, t0, t1); write_bp(bp, 0, t0, t1); }
  }
  asm volatile("s_waitcnt lgkmcnt(0)" ::: "memory");
  {
    const float* p0 = &pbuf[0][0][bl][0];
    xr = p0[j]; xz = p0[8 + j]; xn = p0[16 + j];
  }

  // ---- main loop: scan(c) interleaved with proj(c+1) ----
  #pragma unroll 1
  for (int c = 0; c < NCH; ++c) {
    const int ps = c & 1, pn = ps ^ 1;
    if (c + 2 < NCH) {
      issue(c + 2, c & 1);                            // overwrites xbuf proj(c) used
      asm volatile("s_waitcnt vmcnt(17)" ::: "memory"); // chunk c+1 resident
    } else {
      asm volatile("s_waitcnt vmcnt(0)" ::: "memory");
    }
    const float* bs = &pbuf[ps][0][bl][0];
    if (c + 1 < NCH) {
      f32x4 a0, a1, b0v, b1v;
      proj_bp(0, pn, a0, a1);
      step(bs, 0); step(bs, 1);
      write_bp(0, pn, a0, a1);
      proj_bp(1, pn, b0v, b1v);
      step(bs, 2); step(bs, 3);
      write_bp(1, pn, b0v, b1v);
      proj_bp(2, pn, a0, a1);
      step(bs, 4); step(bs, 5);
      write_bp(2, pn, a0, a1);
      proj_bp(3, pn, b0v, b1v);
      step(bs, 6); step(bs, 7);
      write_bp(3, pn, b0v, b1v);
      asm volatile("s_waitcnt lgkmcnt(0)" ::: "memory");  // pbuf[pn] complete
      const float* p0 = &pbuf[pn][0][bl][0];
      xr = p0[j]; xz = p0[8 + j]; xn = p0[16 + j];        // step0 of scan(c+1)
    } else {
      step(bs, 0); step(bs, 1); step(bs, 2); step(bs, 3);
      step(bs, 4); step(bs, 5); step(bs, 6); step(bs, 7);
    }
  }

  if (j == 0) {
    float o = bd;
    #pragma unroll
    for (int k = 0; k < 8; ++k) o = fmaf(wd[k], g[k], o);  // lane j=0: g[k]=h[k]
    out[b0 + bl] = o;
  }
}

extern "C" void kernel_launch(void* const* d_in, const int* in_sizes, int n_in,
                              void* d_out, int out_size, void* d_ws, size_t ws_size,
                              hipStream_t stream) {
  const float* x     = (const float*)d_in[0];
  const float* w_ih  = (const float*)d_in[1];
  const float* w_hh  = (const float*)d_in[2];
  const float* b_ih  = (const float*)d_in[3];
  const float* b_hh  = (const float*)d_in[4];
  const float* w_dec = (const float*)d_in[5];
  const float* b_dec = (const float*)d_in[6];
  float* out = (float*)d_out;
  (void)d_ws; (void)ws_size;

  k_fused<<<dim3(Bn / 8), dim3(64), 0, stream>>>(x, w_ih, w_hh, b_ih, b_hh,
                                                 w_dec, b_dec, out);
}

// Round 10
// 303.577 us; speedup vs baseline: 1.3561x; 1.0110x over previous
//
#include <hip/hip_runtime.h>

#define Bn 4096
#define Tn 200
#define Fn 64
#define Hn 8
#define Gn 24   // 3*H
#define TC 8    // timesteps per chunk (25*8 = 200, no tail)
#define NCH 25

typedef __attribute__((ext_vector_type(8))) short short8;
typedef __attribute__((ext_vector_type(4))) float f32x4;

// ---------- helpers ----------
__device__ __forceinline__ unsigned short bf16_rne(float f) {
  unsigned u = __float_as_uint(f);
  return (unsigned short)((u + 0x7FFFu + ((u >> 16) & 1u)) >> 16);
}
__device__ __forceinline__ float bf16_to_f(unsigned short s) {
  return __uint_as_float(((unsigned)s) << 16);
}
__device__ __forceinline__ float frcp(float x) {
#if __has_builtin(__builtin_amdgcn_rcpf)
  return __builtin_amdgcn_rcpf(x);
#else
  return 1.0f / x;
#endif
}
__device__ __forceinline__ float fsigmoid(float x) { return frcp(1.0f + __expf(-x)); }
__device__ __forceinline__ float ftanh(float x) {
  x = fminf(30.0f, fmaxf(-30.0f, x));
  float t = __expf(-2.0f * x);
  return (1.0f - t) * frcp(1.0f + t);
}
// cross-lane, all DPP: xor1, xor2 quad_perm; xor7 row_half_mirror (R7-audited)
__device__ __forceinline__ float xf1(float v) {
  return __int_as_float(__builtin_amdgcn_mov_dpp(__float_as_int(v), 0xB1, 0xF, 0xF, true));
}
__device__ __forceinline__ float xf2(float v) {
  return __int_as_float(__builtin_amdgcn_mov_dpp(__float_as_int(v), 0x4E, 0xF, 0xF, true));
}
__device__ __forceinline__ float xf7(float v) {
  return __int_as_float(__builtin_amdgcn_mov_dpp(__float_as_int(v), 0x141, 0xF, 0xF, true));
}
__device__ __forceinline__ unsigned cvt_pk_bf16(float a, float b) {
  unsigned r;
  asm volatile("v_cvt_pk_bf16_f32 %0, %1, %2" : "=v"(r) : "v"(a), "v"(b));
  return r;
}
// trunc-split: hi = bit-truncated bf16 (exact), lo = RNE(residual)  [R9-validated]
__device__ __forceinline__ void split8(const float4& A, const float4& B,
                                       short8& hi, short8& lo) {
  float v[8] = {A.x, A.y, A.z, A.w, B.x, B.y, B.z, B.w};
  union { unsigned u[4]; short8 s; } H, L;
  #pragma unroll
  for (int p = 0; p < 4; ++p) {
    unsigned u0 = __float_as_uint(v[2 * p]), u1 = __float_as_uint(v[2 * p + 1]);
    float h0 = __uint_as_float(u0 & 0xFFFF0000u);
    float h1 = __uint_as_float(u1 & 0xFFFF0000u);
    H.u[p] = (u0 >> 16) | (u1 & 0xFFFF0000u);
    L.u[p] = cvt_pk_bf16(v[2 * p] - h0, v[2 * p + 1] - h1);
  }
  hi = H.s; lo = L.s;
}

// ---------- fused GRU, reg-staged x (no global_load_lds, no xbuf LDS) ----------
// 512 blocks x 1 wave; block owns 8 b. Iter c: [load chunk c+1 -> 16 float4 regs]
// [scan chunk c, gates bulk-preloaded] [split+MFMA+write proj(c+1) -> pbuf ping-pong]
__global__ __launch_bounds__(64) void k_fused(
    const float* __restrict__ x, const float* __restrict__ w_ih,
    const float* __restrict__ w_hh, const float* __restrict__ b_ih,
    const float* __restrict__ b_hh, const float* __restrict__ w_dec,
    const float* __restrict__ b_dec, float* __restrict__ out) {
  __shared__ __align__(16) float pbuf[2][TC][8][Gn];  // 12288 B only

  const int lane = threadIdx.x & 63;
  const int j  = lane & 7;
  const int bl = lane >> 3;
  const int lm = lane & 15;
  const int lh = lane >> 4;
  const int b0 = blockIdx.x * 8;

  // ---- B fragments of w_ih (hi/lo RNE), bias (R6-validated layout) ----
  short8 Bh[2][2], Bl[2][2];
  float bias[2];
  #pragma unroll
  for (int nt = 0; nt < 2; ++nt) {
    int gg0 = nt * 16 + lm;
    bool valid = (gg0 < Gn);
    int gg = valid ? gg0 : 0;
    bias[nt] = valid ? b_ih[gg] : 0.0f;
    #pragma unroll
    for (int kt = 0; kt < 2; ++kt) {
      const float* wp = w_ih + gg * Fn + kt * 32 + lh * 8;
      #pragma unroll
      for (int q = 0; q < 8; ++q) {
        float v = valid ? wp[q] : 0.0f;
        unsigned short hh = bf16_rne(v);
        Bh[nt][kt][q] = (short)hh;
        Bl[nt][kt][q] = (short)bf16_rne(v - bf16_to_f(hh));
      }
    }
  }

  // ---- recurrent weights, butterfly-permuted: whX[k] multiplies h[j^k] ----
  float whr[8], whz[8], whn[8];
  #pragma unroll
  for (int k = 0; k < 8; ++k) {
    int col = j ^ k;
    whr[k] = w_hh[j * 8 + col];
    whz[k] = w_hh[(8 + j) * 8 + col];
    whn[k] = w_hh[(16 + j) * 8 + col];
  }
  const float bhr = b_hh[j], bhz = b_hh[8 + j], bhn = b_hh[16 + j];
  float wd[8];
  #pragma unroll
  for (int k = 0; k < 8; ++k) wd[k] = w_dec[k];
  const float bd = b_dec[0];

  // ---- per-lane global A-fragment base pointers (one per b-pair) ----
  const float* xb = x + (size_t)b0 * Tn * Fn;
  const float* abase[4];
  #pragma unroll
  for (int bp = 0; bp < 4; ++bp)
    abase[bp] = xb + ((size_t)(bp * 2 + (lm >> 3)) * Tn + (lm & 7)) * Fn + lh * 8;

  float4 ld[4][4];  // chunk staging regs: [bp][{kt0 f0-3, kt0 f4-7, kt1 f0-3, kt1 f4-7}]
  auto load_chunk = [&](int c) {
    const int co = c * (TC * Fn);
    #pragma unroll
    for (int bp = 0; bp < 4; ++bp) {
      ld[bp][0] = *(const float4*)(abase[bp] + co);
      ld[bp][1] = *(const float4*)(abase[bp] + co + 4);
      ld[bp][2] = *(const float4*)(abase[bp] + co + 32);
      ld[bp][3] = *(const float4*)(abase[bp] + co + 36);
    }
  };

  // proj current ld -> pbuf[psel]  (split + 12 MFMA per bp + C-write, R6 layout)
  auto proj = [&](int psel) {
    #pragma unroll
    for (int bp = 0; bp < 4; ++bp) {
      short8 Ah0, Al0, Ah1, Al1;
      split8(ld[bp][0], ld[bp][1], Ah0, Al0);
      split8(ld[bp][2], ld[bp][3], Ah1, Al1);
      f32x4 c0 = {0.f, 0.f, 0.f, 0.f}, c1 = {0.f, 0.f, 0.f, 0.f};
      c0 = __builtin_amdgcn_mfma_f32_16x16x32_bf16(Ah0, Bh[0][0], c0, 0, 0, 0);
      c0 = __builtin_amdgcn_mfma_f32_16x16x32_bf16(Ah0, Bl[0][0], c0, 0, 0, 0);
      c0 = __builtin_amdgcn_mfma_f32_16x16x32_bf16(Al0, Bh[0][0], c0, 0, 0, 0);
      c0 = __builtin_amdgcn_mfma_f32_16x16x32_bf16(Ah1, Bh[0][1], c0, 0, 0, 0);
      c0 = __builtin_amdgcn_mfma_f32_16x16x32_bf16(Ah1, Bl[0][1], c0, 0, 0, 0);
      c0 = __builtin_amdgcn_mfma_f32_16x16x32_bf16(Al1, Bh[0][1], c0, 0, 0, 0);
      c1 = __builtin_amdgcn_mfma_f32_16x16x32_bf16(Ah0, Bh[1][0], c1, 0, 0, 0);
      c1 = __builtin_amdgcn_mfma_f32_16x16x32_bf16(Ah0, Bl[1][0], c1, 0, 0, 0);
      c1 = __builtin_amdgcn_mfma_f32_16x16x32_bf16(Al0, Bh[1][0], c1, 0, 0, 0);
      c1 = __builtin_amdgcn_mfma_f32_16x16x32_bf16(Ah1, Bh[1][1], c1, 0, 0, 0);
      c1 = __builtin_amdgcn_mfma_f32_16x16x32_bf16(Ah1, Bl[1][1], c1, 0, 0, 0);
      c1 = __builtin_amdgcn_mfma_f32_16x16x32_bf16(Al1, Bh[1][1], c1, 0, 0, 0);
      #pragma unroll
      for (int i2 = 0; i2 < 4; ++i2) {
        int m = lh * 4 + i2, tl = m & 7, blw = bp * 2 + (m >> 3);
        pbuf[psel][tl][blw][lm] = c0[i2] + bias[0];
        if (lm < 8) pbuf[psel][tl][blw][16 + lm] = c1[i2] + bias[1];
      }
    }
  };

  float g[8];
  #pragma unroll
  for (int k = 0; k < 8; ++k) g[k] = 0.0f;

  // ---- prologue: proj chunk 0 ----
  load_chunk(0);
  proj(0);

  #pragma unroll 1
  for (int c = 0; c < NCH; ++c) {
    const int ps = c & 1;
    // bulk gate preload for scan(c) (24 ds_read, off the per-step critical path)
    float sr[TC], sz[TC], sn[TC];
    {
      const float* pp = &pbuf[ps][0][bl][0];
      #pragma unroll
      for (int t = 0; t < TC; ++t) {
        sr[t] = pp[t * (8 * Gn) + j];
        sz[t] = pp[t * (8 * Gn) + 8 + j];
        sn[t] = pp[t * (8 * Gn) + 16 + j];
      }
    }
    // issue next chunk's global loads; 8 scan steps hide the latency
    if (c + 1 < NCH) load_chunk(c + 1);

    // ---- scan 8 steps (validated butterfly, gates in regs) ----
    #pragma unroll
    for (int t = 0; t < TC; ++t) {
      float ghr = bhr, ghz = bhz, ghn = bhn;
      const int ko[8] = {0, 1, 2, 3, 7, 6, 5, 4};  // deepest-DPP value last
      #pragma unroll
      for (int q = 0; q < 8; ++q) {
        int k = ko[q];
        ghr = fmaf(whr[k], g[k], ghr);
        ghz = fmaf(whz[k], g[k], ghz);
        ghn = fmaf(whn[k], g[k], ghn);
      }
      float r  = fsigmoid(sr[t] + ghr);
      float z  = fsigmoid(sz[t] + ghz);
      float nv = ftanh(sn[t] + r * ghn);
      float hj = fmaf(z, g[0] - nv, nv);   // (1-z)*n + z*h
      g[0] = hj;
      g[1] = xf1(g[0]); g[2] = xf2(g[0]); g[3] = xf2(g[1]);
      g[7] = xf7(g[0]); g[6] = xf7(g[1]); g[5] = xf7(g[2]); g[4] = xf7(g[3]);
    }

    // ---- proj chunk c+1 into the other pbuf (compiler handles lgkm deps) ----
    if (c + 1 < NCH) proj(ps ^ 1);
  }

  if (j == 0) {
    float o = bd;
    #pragma unroll
    for (int k = 0; k < 8; ++k) o = fmaf(wd[k], g[k], o);  // lane j=0: g[k]=h[k]
    out[b0 + bl] = o;
  }
}

extern "C" void kernel_launch(void* const* d_in, const int* in_sizes, int n_in,
                              void* d_out, int out_size, void* d_ws, size_t ws_size,
                              hipStream_t stream) {
  const float* x     = (const float*)d_in[0];
  const float* w_ih  = (const float*)d_in[1];
  const float* w_hh  = (const float*)d_in[2];
  const float* b_ih  = (const float*)d_in[3];
  const float* b_hh  = (const float*)d_in[4];
  const float* w_dec = (const float*)d_in[5];
  const float* b_dec = (const float*)d_in[6];
  float* out = (float*)d_out;
  (void)d_ws; (void)ws_size;

  k_fused<<<dim3(Bn / 8), dim3(64), 0, stream>>>(x, w_ih, w_hh, b_ih, b_hh,
                                                 w_dec, b_dec, out);
}